// Round 18
// baseline (360.826 us; speedup 1.0000x reference)
//
#include <hip/hip_runtime.h>
#include <hip/hip_bf16.h>

#define NN 50000
#define EE 800000
#define ET (EE + NN)
#define F_IN 128
#define HID 32
#define H1 4
#define H2 8
#define E_DEC 100000
#define NEG_SLOPE 0.2f

typedef __attribute__((ext_vector_type(8))) short short8;
typedef __attribute__((ext_vector_type(4))) float floatx4;

__device__ __forceinline__ unsigned short f2b(float f) {
    __hip_bfloat16 h = __float2bfloat16(f);
    return *reinterpret_cast<unsigned short*>(&h);
}
__device__ __forceinline__ float b2f(unsigned short u) {
    return __uint_as_float(((unsigned int)u) << 16);
}

// ============ merged: XCD-local histogram+rank + pack W1 + pack W2 ============
__device__ __forceinline__ void packW_one(const float* __restrict__ W,
                                          unsigned short* __restrict__ Wp, int OUT, int id) {
    const int ctg = id >> 8;
    const int ln = id & 63;
    const int col = ctg * 16 + (ln & 15);
    const int k0 = ((id >> 6) & 3) * 32 + ((ln >> 4) & 3) * 8;
    ushort4 lo, hi;
    lo.x = f2b(W[(k0 + 0) * OUT + col]);
    lo.y = f2b(W[(k0 + 1) * OUT + col]);
    lo.z = f2b(W[(k0 + 2) * OUT + col]);
    lo.w = f2b(W[(k0 + 3) * OUT + col]);
    hi.x = f2b(W[(k0 + 4) * OUT + col]);
    hi.y = f2b(W[(k0 + 5) * OUT + col]);
    hi.z = f2b(W[(k0 + 6) * OUT + col]);
    hi.w = f2b(W[(k0 + 7) * OUT + col]);
    ((ushort4*)Wp)[id * 2] = lo;
    ((ushort4*)Wp)[id * 2 + 1] = hi;
}

#define HIST_BLOCKS ((EE / 4 + 255) / 256)   // 782
#define PACK_BLOCKS ((6144 + 255) / 256)     // 24

__global__ void hist_pack_k(const int* __restrict__ ei, int* __restrict__ counts_p,
                            const int* __restrict__ probe, int* __restrict__ rank,
                            const float* __restrict__ W1, unsigned short* __restrict__ wp1,
                            const float* __restrict__ W2, unsigned short* __restrict__ wp2) {
    if (blockIdx.x < HIST_BLOCKS) {
        const int t = blockIdx.x * 256 + threadIdx.x;
        if (t >= EE / 4) return;
        const int pv = probe[0];
        int* cp = counts_p + (blockIdx.x & 7) * NN;
        const int4 d4 = ((const int4*)(ei + EE))[t];
        int4 r4;
        r4.x = atomicAdd(&cp[d4.x], 1) - pv;
        r4.y = atomicAdd(&cp[d4.y], 1) - pv;
        r4.z = atomicAdd(&cp[d4.z], 1) - pv;
        r4.w = atomicAdd(&cp[d4.w], 1) - pv;
        ((int4*)rank)[t] = r4;
    } else {
        const int id = (blockIdx.x - HIST_BLOCKS) * 256 + threadIdx.x;
        if (id < 2048) packW_one(W1, wp1, 128, id);
        else if (id < 6144) packW_one(W2, wp2, 256, id - 2048);
    }
}

// ============ hierarchical exclusive scan over node degrees ============
__global__ void scan1_k(const int* __restrict__ counts_p, const int* __restrict__ probe,
                        int* __restrict__ bsum) {
    __shared__ int sh[256];
    const unsigned pv = (unsigned)probe[0];
    int t = threadIdx.x;
    int i = blockIdx.x * 256 + t;
    int deg = 0;
    if (i < NN) {
        unsigned sum = 0;
#pragma unroll
        for (int s = 0; s < 8; ++s) sum += (unsigned)counts_p[s * NN + i];
        deg = (int)(sum - 8u * pv) + 1;
    }
    sh[t] = deg;
    __syncthreads();
    for (int off = 128; off > 0; off >>= 1) {
        if (t < off) sh[t] += sh[t + off];
        __syncthreads();
    }
    if (t == 0) bsum[blockIdx.x] = sh[0];
}

// scan2 also zeroes the degree-histogram bins (dbin) for the later counting sort.
__global__ void scan2_k(int* __restrict__ bsum, int nb, int* __restrict__ start,
                        int* __restrict__ dbin) {
    __shared__ int sh[256];
    int t = threadIdx.x;
    dbin[t] = 0;
    int v = (t < nb) ? bsum[t] : 0;
    sh[t] = v;
    __syncthreads();
    for (int off = 1; off < 256; off <<= 1) {
        int u = (t >= off) ? sh[t - off] : 0;
        __syncthreads();
        sh[t] += u;
        __syncthreads();
    }
    if (t < nb) bsum[t] = sh[t] - v;
    if (t == 0) start[NN] = ET;
}

// scan3: start[], per-slice offsets offs[s][i], self-loop in LAST slot, and
// degree-histogram accumulation (LDS-merged) for the counting sort.
__global__ void scan3_k(const int* __restrict__ counts_p, const int* __restrict__ probe,
                        const int* __restrict__ bsum, int* __restrict__ start,
                        int* __restrict__ offs, int* __restrict__ csr,
                        int* __restrict__ dbin) {
    __shared__ int sh[256];
    __shared__ int lh[256];
    const unsigned pv = (unsigned)probe[0];
    int t = threadIdx.x;
    int i = blockIdx.x * 256 + t;
    int part[8];
    int deg = 0;
    if (i < NN) {
        deg = 1;
#pragma unroll
        for (int s = 0; s < 8; ++s) {
            part[s] = (int)((unsigned)counts_p[s * NN + i] - pv);
            deg += part[s];
        }
    }
    lh[t] = 0;
    sh[t] = deg;
    __syncthreads();
    for (int off = 1; off < 256; off <<= 1) {
        int u = (t >= off) ? sh[t - off] : 0;
        __syncthreads();
        sh[t] += u;
        __syncthreads();
    }
    int excl = sh[t] - deg + bsum[blockIdx.x];
    if (i < NN) {
        start[i] = excl;
        int o = excl;
#pragma unroll
        for (int s = 0; s < 8; ++s) {
            offs[s * NN + i] = o;
            o += part[s];
        }
        csr[o] = i;   // self-loop last
        atomicAdd(&lh[deg > 255 ? 255 : deg], 1);
    }
    __syncthreads();
    if (lh[t] > 0) atomicAdd(&dbin[t], lh[t]);
}

// ============ counting-sort: 1-block exclusive scan of dbin -> dcur ============
__global__ void dscan_k(const int* __restrict__ dbin, int* __restrict__ dcur) {
    __shared__ int sh[256];
    int t = threadIdx.x;
    int v = dbin[t];
    sh[t] = v;
    __syncthreads();
    for (int off = 1; off < 256; off <<= 1) {
        int u = (t >= off) ? sh[t - off] : 0;
        __syncthreads();
        sh[t] += u;
        __syncthreads();
    }
    dcur[t] = sh[t] - v;
}

// ============ counting-sort scatter: perm = nodes sorted by degree ============
__global__ void dsort_k(const int* __restrict__ start, int* __restrict__ dcur,
                        int* __restrict__ perm) {
    __shared__ int lh[256];
    __shared__ int lbase[256];
    const int t = threadIdx.x;
    const int i = blockIdx.x * 256 + t;
    lh[t] = 0;
    __syncthreads();
    int deg = 0, lr = 0;
    if (i < NN) {
        deg = start[i + 1] - start[i];
        if (deg > 255) deg = 255;
        lr = atomicAdd(&lh[deg], 1);
    }
    __syncthreads();
    const int cnt = lh[t];
    if (cnt > 0) lbase[t] = atomicAdd(&dcur[t], cnt);
    __syncthreads();
    if (i < NN) perm[lbase[deg] + lr] = i;
}

// ============ scatter: rank+offs based, NO atomics ============
__global__ void scatter_k(const int* __restrict__ ei, const int* __restrict__ rank,
                          const int* __restrict__ offs, int* __restrict__ csr) {
    const int t = blockIdx.x * 256 + threadIdx.x;
    if (t >= EE / 4) return;
    const int* off = offs + (blockIdx.x & 7) * NN;
    const int4 s4 = ((const int4*)ei)[t];
    const int4 d4 = ((const int4*)(ei + EE))[t];
    const int4 r4 = ((const int4*)rank)[t];
    csr[off[d4.x] + r4.x] = s4.x;
    csr[off[d4.y] + r4.y] = s4.y;
    csr[off[d4.z] + r4.z] = s4.z;
    csr[off[d4.w] + r4.w] = s4.w;
}

// ============ MFMA GEMM + fused al epilogue ============
// H out: HSCH-ch slices (HSCH=OUT -> row-major).
// als/ald: ALS_HM ? head-major [hd*NN+row] : node-major [row*H+hd].
template <int OUT, int H, int CT, bool F32IN, int HSCH, bool ALS_HM>
__global__ void gemm_k(const void* __restrict__ Xin, const unsigned short* __restrict__ Wp,
                       const float* __restrict__ a_src, const float* __restrict__ a_dst,
                       unsigned short* __restrict__ Hout, float* __restrict__ als,
                       float* __restrict__ ald) {
    const int wave = threadIdx.x >> 6;
    const int lane = threadIdx.x & 63;
    const int quad = lane >> 4;
    const int rl = lane & 15;
    const int r0 = blockIdx.x * 64;
    floatx4 acc[4][CT];
#pragma unroll
    for (int rt = 0; rt < 4; ++rt)
#pragma unroll
        for (int ct = 0; ct < CT; ++ct) acc[rt][ct] = {0.f, 0.f, 0.f, 0.f};

#pragma unroll
    for (int ks = 0; ks < 4; ++ks) {
        short8 a[4];
        const int c0k = ks * 32 + quad * 8;
#pragma unroll
        for (int rt = 0; rt < 4; ++rt) {
            int row = r0 + rt * 16 + rl;
            row = row < NN ? row : NN - 1;
            if (F32IN) {
                const float4* xp =
                    (const float4*)((const float*)Xin + (long long)row * 128 + c0k);
                const float4 v0 = xp[0];
                const float4 v1 = xp[1];
                short8 tt;
                tt[0] = (short)f2b(v0.x);
                tt[1] = (short)f2b(v0.y);
                tt[2] = (short)f2b(v0.z);
                tt[3] = (short)f2b(v0.w);
                tt[4] = (short)f2b(v1.x);
                tt[5] = (short)f2b(v1.y);
                tt[6] = (short)f2b(v1.z);
                tt[7] = (short)f2b(v1.w);
                a[rt] = tt;
            } else {
                a[rt] = *(const short8*)((const unsigned short*)Xin +
                                         (long long)row * 128 + c0k);
            }
        }
#pragma unroll
        for (int ct = 0; ct < CT; ++ct) {
            const int ctg = wave * CT + ct;
            const short8 b = *(const short8*)(Wp + (((ctg * 4 + ks) * 64 + lane) << 3));
#pragma unroll
            for (int rt = 0; rt < 4; ++rt)
                acc[rt][ct] = __builtin_amdgcn_mfma_f32_16x16x32_bf16(a[rt], b, acc[rt][ct], 0, 0, 0);
        }
    }
#pragma unroll
    for (int rt = 0; rt < 4; ++rt) {
        const int rowbase = r0 + rt * 16 + quad * 4;
#pragma unroll
        for (int ct = 0; ct < CT; ++ct) {
            const int col = (wave * CT + ct) * 16 + rl;
            const long long sb = (long long)(col / HSCH) * NN * HSCH + (col % HSCH);
#pragma unroll
            for (int r = 0; r < 4; ++r) {
                const int row = rowbase + r;
                if (row < NN) Hout[sb + (long long)row * HSCH] = f2b(acc[rt][ct][r]);
            }
        }
    }
    float asv[CT], adv[CT];
#pragma unroll
    for (int ct = 0; ct < CT; ++ct) {
        const int col = (wave * CT + ct) * 16 + rl;
        asv[ct] = a_src[col];
        adv[ct] = a_dst[col];
    }
#pragma unroll
    for (int rt = 0; rt < 4; ++rt) {
#pragma unroll
        for (int r = 0; r < 4; ++r) {
            const int row = r0 + rt * 16 + quad * 4 + r;
            float ps[CT / 2], pd[CT / 2];
#pragma unroll
            for (int hh = 0; hh < CT / 2; ++hh) {
                ps[hh] = acc[rt][2 * hh][r] * asv[2 * hh] + acc[rt][2 * hh + 1][r] * asv[2 * hh + 1];
                pd[hh] = acc[rt][2 * hh][r] * adv[2 * hh] + acc[rt][2 * hh + 1][r] * adv[2 * hh + 1];
#pragma unroll
                for (int m = 8; m >= 1; m >>= 1) {
                    ps[hh] += __shfl_xor(ps[hh], m, 64);
                    pd[hh] += __shfl_xor(pd[hh], m, 64);
                }
            }
            if (rl == 0 && row < NN) {
#pragma unroll
                for (int hh = 0; hh < CT / 2; ++hh) {
                    const int hd = wave * (CT / 2) + hh;
                    const long long ai = ALS_HM ? ((long long)hd * NN + row)
                                                : ((long long)row * H + hd);
                    als[ai] = ps[hh];
                    ald[ai] = pd[hh];
                }
            }
        }
    }
}

// ============ conv1 gather: row-major, one wave/node, 8/4/1 unroll, EPW=2 ============
__global__ void gather1_k(const int* __restrict__ start, const int* __restrict__ csr,
                          const float* __restrict__ als, const float* __restrict__ ald,
                          const unsigned short* __restrict__ Hin,
                          const float* __restrict__ bias, unsigned short* __restrict__ outp) {
    const int d = blockIdx.x;
    const int lane = threadIdx.x;
    const int cl = lane & 31;
    const int slot = lane >> 5;
    const int hd = cl >> 3;
    const int beg = start[d], end = start[d + 1];
    const float aldd = ald[(long long)d * H1 + hd];
    float a0 = 0.f, a1 = 0.f, a2 = 0.f, a3 = 0.f, den = 0.f;
    int i = beg + slot;
    for (; i + 7 * 2 < end; i += 8 * 2) {
        int s[8];
        float l[8];
        ushort4 hv[8];
#pragma unroll
        for (int k = 0; k < 8; ++k) s[k] = csr[i + k * 2];
#pragma unroll
        for (int k = 0; k < 8; ++k) l[k] = als[(long long)s[k] * H1 + hd] + aldd;
#pragma unroll
        for (int k = 0; k < 8; ++k) hv[k] = *(const ushort4*)(Hin + (long long)s[k] * 128 + cl * 4);
#pragma unroll
        for (int k = 0; k < 8; ++k) {
            float lg = l[k] > 0.f ? l[k] : NEG_SLOPE * l[k];
            const float w = __expf(lg);
            den += w;
            a0 += w * b2f(hv[k].x);
            a1 += w * b2f(hv[k].y);
            a2 += w * b2f(hv[k].z);
            a3 += w * b2f(hv[k].w);
        }
    }
    for (; i + 3 * 2 < end; i += 4 * 2) {
        int s[4];
        float l[4];
        ushort4 hv[4];
#pragma unroll
        for (int k = 0; k < 4; ++k) s[k] = csr[i + k * 2];
#pragma unroll
        for (int k = 0; k < 4; ++k) l[k] = als[(long long)s[k] * H1 + hd] + aldd;
#pragma unroll
        for (int k = 0; k < 4; ++k) hv[k] = *(const ushort4*)(Hin + (long long)s[k] * 128 + cl * 4);
#pragma unroll
        for (int k = 0; k < 4; ++k) {
            float lg = l[k] > 0.f ? l[k] : NEG_SLOPE * l[k];
            const float w = __expf(lg);
            den += w;
            a0 += w * b2f(hv[k].x);
            a1 += w * b2f(hv[k].y);
            a2 += w * b2f(hv[k].z);
            a3 += w * b2f(hv[k].w);
        }
    }
    for (; i < end; i += 2) {
        const int s = csr[i];
        float lg = als[(long long)s * H1 + hd] + aldd;
        lg = lg > 0.f ? lg : NEG_SLOPE * lg;
        const float w = __expf(lg);
        const ushort4 hv = *(const ushort4*)(Hin + (long long)s * 128 + cl * 4);
        den += w;
        a0 += w * b2f(hv.x);
        a1 += w * b2f(hv.y);
        a2 += w * b2f(hv.z);
        a3 += w * b2f(hv.w);
    }
    a0 += __shfl_xor(a0, 32, 64);
    a1 += __shfl_xor(a1, 32, 64);
    a2 += __shfl_xor(a2, 32, 64);
    a3 += __shfl_xor(a3, 32, 64);
    den += __shfl_xor(den, 32, 64);
    if (lane < 32) {
        const float inv = 1.f / (den + 1e-16f);
        const int c0 = cl * 4;
        float v0 = a0 * inv + bias[c0];
        float v1 = a1 * inv + bias[c0 + 1];
        float v2 = a2 * inv + bias[c0 + 2];
        float v3 = a3 * inv + bias[c0 + 3];
        v0 = v0 > 0.f ? v0 : 0.f;
        v1 = v1 > 0.f ? v1 : 0.f;
        v2 = v2 > 0.f ? v2 : 0.f;
        v3 = v3 > 0.f ? v3 : 0.f;
        ushort4 o;
        o.x = f2b(v0);
        o.y = f2b(v1);
        o.z = f2b(v2);
        o.w = f2b(v3);
        *(ushort4*)(outp + (long long)d * 128 + c0) = o;
    }
}

// ============ conv2 gather: XCD-sliced, slot-per-node, DEGREE-SORTED ============
// grid = 8 * ceil(NN/32); slice s = blockIdx&7 (XCD-affine); wave = 8 slots x 8
// lanes; slot owns node perm[idx] (degree-sorted -> slots in a wave have ~equal
// degree, no divergence). h2s slice-major [s][node][32]; als/ald head-major.
__global__ void gather2s_k(const int* __restrict__ start, const int* __restrict__ csr,
                           const int* __restrict__ perm,
                           const float* __restrict__ als, const float* __restrict__ ald,
                           const unsigned short* __restrict__ h2s,
                           const float* __restrict__ bias, unsigned short* __restrict__ z2) {
    const int s = blockIdx.x & 7;
    const int g = blockIdx.x >> 3;
    const int wave = threadIdx.x >> 6;
    const int lane = threadIdx.x & 63;
    const int slot = lane >> 3;
    const int cl = lane & 7;
    const int idx = g * 32 + wave * 8 + slot;
    if (idx >= NN) return;
    const int d = perm[idx];
    const float* alsh = als + (long long)s * NN;
    const unsigned short* hsl = h2s + (long long)s * NN * 32 + cl * 4;
    const int beg = start[d], end = start[d + 1];
    const float aldd = ald[(long long)s * NN + d];
    float a0 = 0.f, a1 = 0.f, a2 = 0.f, a3 = 0.f, den = 0.f;
    int i = beg;
    for (; i + 7 < end; i += 8) {
        int sx[8];
        float l[8];
        ushort4 hv[8];
#pragma unroll
        for (int k = 0; k < 8; ++k) sx[k] = csr[i + k];
#pragma unroll
        for (int k = 0; k < 8; ++k) l[k] = alsh[sx[k]] + aldd;
#pragma unroll
        for (int k = 0; k < 8; ++k) hv[k] = *(const ushort4*)(hsl + (long long)sx[k] * 32);
#pragma unroll
        for (int k = 0; k < 8; ++k) {
            float lg = l[k] > 0.f ? l[k] : NEG_SLOPE * l[k];
            const float w = __expf(lg);
            den += w;
            a0 += w * b2f(hv[k].x);
            a1 += w * b2f(hv[k].y);
            a2 += w * b2f(hv[k].z);
            a3 += w * b2f(hv[k].w);
        }
    }
    for (; i + 3 < end; i += 4) {
        int sx[4];
        float l[4];
        ushort4 hv[4];
#pragma unroll
        for (int k = 0; k < 4; ++k) sx[k] = csr[i + k];
#pragma unroll
        for (int k = 0; k < 4; ++k) l[k] = alsh[sx[k]] + aldd;
#pragma unroll
        for (int k = 0; k < 4; ++k) hv[k] = *(const ushort4*)(hsl + (long long)sx[k] * 32);
#pragma unroll
        for (int k = 0; k < 4; ++k) {
            float lg = l[k] > 0.f ? l[k] : NEG_SLOPE * l[k];
            const float w = __expf(lg);
            den += w;
            a0 += w * b2f(hv[k].x);
            a1 += w * b2f(hv[k].y);
            a2 += w * b2f(hv[k].z);
            a3 += w * b2f(hv[k].w);
        }
    }
    for (; i < end; ++i) {
        const int sx = csr[i];
        float lg = alsh[sx] + aldd;
        lg = lg > 0.f ? lg : NEG_SLOPE * lg;
        const float w = __expf(lg);
        const ushort4 hv = *(const ushort4*)(hsl + (long long)sx * 32);
        den += w;
        a0 += w * b2f(hv.x);
        a1 += w * b2f(hv.y);
        a2 += w * b2f(hv.z);
        a3 += w * b2f(hv.w);
    }
    const float inv = 1.f / (den + 1e-16f);
    const float4 bv = *(const float4*)(bias + s * 32 + cl * 4);
    ushort4 o;
    o.x = f2b(a0 * inv + bv.x);
    o.y = f2b(a1 * inv + bv.y);
    o.z = f2b(a2 * inv + bv.z);
    o.w = f2b(a3 * inv + bv.w);
    *(ushort4*)(z2 + (long long)d * 256 + s * 32 + cl * 4) = o;
}

// ============ decode: XCD-sliced partial dots ============
__global__ void decode_s_k(const int* __restrict__ pei, const int* __restrict__ nei,
                           const unsigned short* __restrict__ z2, float* __restrict__ part) {
    const int s = blockIdx.x & 7;
    const int g = blockIdx.x >> 3;
    const int wave = threadIdx.x >> 6, lane = threadIdx.x & 63;
    const int slot = lane >> 3, cl = lane & 7;
    const int idx = g * 32 + wave * 8 + slot;
    if (idx >= 2 * E_DEC) return;
    int a, b;
    if (idx < E_DEC) {
        a = pei[idx];
        b = pei[E_DEC + idx];
    } else {
        const int j = idx - E_DEC;
        a = nei[j];
        b = nei[E_DEC + j];
    }
    const ushort4 ua = *(const ushort4*)(z2 + (long long)a * 256 + s * 32 + cl * 4);
    const ushort4 ub = *(const ushort4*)(z2 + (long long)b * 256 + s * 32 + cl * 4);
    float sum = b2f(ua.x) * b2f(ub.x) + b2f(ua.y) * b2f(ub.y) +
                b2f(ua.z) * b2f(ub.z) + b2f(ua.w) * b2f(ub.w);
    sum += __shfl_xor(sum, 4, 64);
    sum += __shfl_xor(sum, 2, 64);
    sum += __shfl_xor(sum, 1, 64);
    if (cl == 0) part[(long long)s * (2 * E_DEC) + idx] = sum;
}

__global__ void reduce_k(const float* __restrict__ part, float* __restrict__ out) {
    const int i = blockIdx.x * 256 + threadIdx.x;
    if (i >= 2 * E_DEC) return;
    float s = 0.f;
#pragma unroll
    for (int k = 0; k < 8; ++k) s += part[(long long)k * (2 * E_DEC) + i];
    out[i] = s;
}

extern "C" void kernel_launch(void* const* d_in, const int* in_sizes, int n_in,
                              void* d_out, int out_size, void* d_ws, size_t ws_size,
                              hipStream_t stream) {
    const float* x = (const float*)d_in[0];
    const int* ei = (const int*)d_in[1];
    const int* pei = (const int*)d_in[2];
    const int* nei = (const int*)d_in[3];
    const float* W1 = (const float*)d_in[4];
    const float* as1 = (const float*)d_in[5];
    const float* ad1 = (const float*)d_in[6];
    const float* b1 = (const float*)d_in[7];
    const float* W2 = (const float*)d_in[8];
    const float* as2 = (const float*)d_in[9];
    const float* ad2 = (const float*)d_in[10];
    const float* b2 = (const float*)d_in[11];
    float* out = (float*)d_out;

    // ---- workspace layout ----
    unsigned short* h1 = (unsigned short*)d_ws;              // NN*128 row-major
    unsigned short* h2s = h1 + (long long)NN * 128;          // NN*256 slice-major (8x32)
    unsigned short* z2 = h2s + (long long)NN * 256;          // NN*256 row-major
    unsigned short* z1 = z2 + (long long)NN * 256;           // NN*128 row-major
    unsigned short* wp1 = z1 + (long long)NN * 128;          // 128*128
    unsigned short* wp2 = wp1 + 128 * 128;                   // 128*256
    float* als1 = (float*)(wp2 + 128 * 256);                 // NN*H1 node-major
    float* ald1 = als1 + NN * H1;
    float* als2 = ald1 + NN * H1;                            // H2*NN head-major
    float* ald2 = als2 + NN * H2;
    float* part = ald2 + NN * H2;                            // 8 * 2*E_DEC
    int* counts_p = (int*)(part + 8 * 2 * E_DEC);            // 8*NN
    int* start = counts_p + 8 * NN;                          // NN+1
    int* offs = start + NN + 1;                              // 8*NN
    int* rank = offs + 8 * NN;                               // EE
    int* bsum = rank + EE;                                   // 256
    int* dbin = bsum + 256;                                  // 256
    int* dcur = dbin + 256;                                  // 256
    int* perm = dcur + 256;                                  // NN
    int* csr = perm + NN;                                    // ET
    int* probe = csr + ET;                                   // 1 (never written)

    const int NB = (NN + 255) / 256;  // 196

    // ---- CSR build + degree sort + W pack ----
    hist_pack_k<<<HIST_BLOCKS + PACK_BLOCKS, 256, 0, stream>>>(
        ei, counts_p, probe, rank, W1, wp1, W2, wp2);
    scan1_k<<<NB, 256, 0, stream>>>(counts_p, probe, bsum);
    scan2_k<<<1, 256, 0, stream>>>(bsum, NB, start, dbin);
    scan3_k<<<NB, 256, 0, stream>>>(counts_p, probe, bsum, start, offs, csr, dbin);
    dscan_k<<<1, 256, 0, stream>>>(dbin, dcur);
    dsort_k<<<NB, 256, 0, stream>>>(start, dcur, perm);
    scatter_k<<<HIST_BLOCKS, 256, 0, stream>>>(ei, rank, offs, csr);

    // ---- conv1: row-major h1, node-major als ----
    gemm_k<128, H1, 2, true, 128, false><<<(NN + 63) / 64, 256, 0, stream>>>(
        x, wp1, as1, ad1, h1, als1, ald1);
    gather1_k<<<NN, 64, 0, stream>>>(start, csr, als1, ald1, h1, b1, z1);

    // ---- conv2: slice-major h2, head-major als; degree-sorted sliced gather ----
    gemm_k<256, H2, 4, false, 32, true><<<(NN + 63) / 64, 256, 0, stream>>>(
        z1, wp2, as2, ad2, h2s, als2, ald2);
    gather2s_k<<<8 * ((NN + 31) / 32), 256, 0, stream>>>(
        start, csr, perm, als2, ald2, h2s, b2, z2);

    // ---- decode: XCD-sliced partials + reduce ----
    decode_s_k<<<8 * ((2 * E_DEC + 31) / 32), 256, 0, stream>>>(pei, nei, z2, part);
    reduce_k<<<(2 * E_DEC + 255) / 256, 256, 0, stream>>>(part, out);
}

// Round 19
// 339.744 us; speedup vs baseline: 1.0621x; 1.0621x over previous
//
#include <hip/hip_runtime.h>
#include <hip/hip_bf16.h>

#define NN 50000
#define EE 800000
#define ET (EE + NN)
#define F_IN 128
#define HID 32
#define H1 4
#define H2 8
#define E_DEC 100000
#define NEG_SLOPE 0.2f
#define NB_SCAN 196   // ceil(NN/256)

typedef __attribute__((ext_vector_type(8))) short short8;
typedef __attribute__((ext_vector_type(4))) float floatx4;

__device__ __forceinline__ unsigned short f2b(float f) {
    __hip_bfloat16 h = __float2bfloat16(f);
    return *reinterpret_cast<unsigned short*>(&h);
}
__device__ __forceinline__ float b2f(unsigned short u) {
    return __uint_as_float(((unsigned int)u) << 16);
}

// ============ merged: XCD-local histogram+rank + pack W1 + pack W2 + init ============
__device__ __forceinline__ void packW_one(const float* __restrict__ W,
                                          unsigned short* __restrict__ Wp, int OUT, int id) {
    const int ctg = id >> 8;
    const int ln = id & 63;
    const int col = ctg * 16 + (ln & 15);
    const int k0 = ((id >> 6) & 3) * 32 + ((ln >> 4) & 3) * 8;
    ushort4 lo, hi;
    lo.x = f2b(W[(k0 + 0) * OUT + col]);
    lo.y = f2b(W[(k0 + 1) * OUT + col]);
    lo.z = f2b(W[(k0 + 2) * OUT + col]);
    lo.w = f2b(W[(k0 + 3) * OUT + col]);
    hi.x = f2b(W[(k0 + 4) * OUT + col]);
    hi.y = f2b(W[(k0 + 5) * OUT + col]);
    hi.z = f2b(W[(k0 + 6) * OUT + col]);
    hi.w = f2b(W[(k0 + 7) * OUT + col]);
    ((ushort4*)Wp)[id * 2] = lo;
    ((ushort4*)Wp)[id * 2 + 1] = hi;
}

#define HIST_BLOCKS ((EE / 4 + 255) / 256)   // 782
#define PACK_BLOCKS ((6144 + 255) / 256)     // 24

__global__ void hist_pack_k(const int* __restrict__ ei, int* __restrict__ counts_p,
                            const int* __restrict__ probe, int* __restrict__ rank,
                            const float* __restrict__ W1, unsigned short* __restrict__ wp1,
                            const float* __restrict__ W2, unsigned short* __restrict__ wp2,
                            int* __restrict__ done) {
    if (blockIdx.x < HIST_BLOCKS) {
        const int t = blockIdx.x * 256 + threadIdx.x;
        if (t >= EE / 4) return;
        const int pv = probe[0];
        int* cp = counts_p + (blockIdx.x & 7) * NN;
        const int4 d4 = ((const int4*)(ei + EE))[t];
        int4 r4;
        r4.x = atomicAdd(&cp[d4.x], 1) - pv;
        r4.y = atomicAdd(&cp[d4.y], 1) - pv;
        r4.z = atomicAdd(&cp[d4.z], 1) - pv;
        r4.w = atomicAdd(&cp[d4.w], 1) - pv;
        ((int4*)rank)[t] = r4;
    } else {
        const int id = (blockIdx.x - HIST_BLOCKS) * 256 + threadIdx.x;
        if (id < 2048) packW_one(W1, wp1, 128, id);
        else if (id < 6144) packW_one(W2, wp2, 256, id - 2048);
        else if (id == 6144) done[0] = 0;   // extra init block; visible at next kernel
    }
}

// ============ FUSED exclusive scan over node degrees (single kernel) ============
// 196 blocks (<= CU count => all co-resident). Each block: local scan of its 256
// degrees -> publish aggregate -> barrier via done-counter -> LDS-scan the 196
// aggregates for the global prefix -> write start/offs/csr-selfloop.
__global__ void scanfused_k(const int* __restrict__ counts_p, const int* __restrict__ probe,
                            int* __restrict__ agg, int* __restrict__ done,
                            int* __restrict__ start, int* __restrict__ offs,
                            int* __restrict__ csr) {
    __shared__ int sh[256];
    __shared__ int sh2[256];
    const unsigned pv = (unsigned)probe[0];
    const int t = threadIdx.x;
    const int b = blockIdx.x;
    const int i = b * 256 + t;
    int part[8];
    int deg = 0;
    if (i < NN) {
        deg = 1;
#pragma unroll
        for (int s = 0; s < 8; ++s) {
            part[s] = (int)((unsigned)counts_p[s * NN + i] - pv);
            deg += part[s];
        }
    }
    sh[t] = deg;
    __syncthreads();
    for (int off = 1; off < 256; off <<= 1) {
        int u = (t >= off) ? sh[t - off] : 0;
        __syncthreads();
        sh[t] += u;
        __syncthreads();
    }
    // publish this block's total, then wait for all blocks
    if (t == 0) {
        agg[b] = sh[255];
        __threadfence();               // device-scope: make agg visible
        atomicAdd(&done[0], 1);
        while (atomicAdd(&done[0], 0) < NB_SCAN) __builtin_amdgcn_s_sleep(8);
    }
    __syncthreads();
    // scan all aggregates for this block's global exclusive prefix
    sh2[t] = (t < NB_SCAN) ? agg[t] : 0;
    __syncthreads();
    for (int off = 1; off < 256; off <<= 1) {
        int u = (t >= off) ? sh2[t - off] : 0;
        __syncthreads();
        sh2[t] += u;
        __syncthreads();
    }
    const int base = (b > 0) ? sh2[b - 1] : 0;
    const int excl = base + sh[t] - deg;
    if (i < NN) {
        start[i] = excl;
        int o = excl;
#pragma unroll
        for (int s = 0; s < 8; ++s) {
            offs[s * NN + i] = o;
            o += part[s];
        }
        csr[o] = i;   // self-loop last (o = excl + deg - 1)
    }
    if (b == 0 && t == 0) start[NN] = ET;
}

// ============ scatter: rank+offs based, NO atomics ============
__global__ void scatter_k(const int* __restrict__ ei, const int* __restrict__ rank,
                          const int* __restrict__ offs, int* __restrict__ csr) {
    const int t = blockIdx.x * 256 + threadIdx.x;
    if (t >= EE / 4) return;
    const int* off = offs + (blockIdx.x & 7) * NN;
    const int4 s4 = ((const int4*)ei)[t];
    const int4 d4 = ((const int4*)(ei + EE))[t];
    const int4 r4 = ((const int4*)rank)[t];
    csr[off[d4.x] + r4.x] = s4.x;
    csr[off[d4.y] + r4.y] = s4.y;
    csr[off[d4.z] + r4.z] = s4.z;
    csr[off[d4.w] + r4.w] = s4.w;
}

// ============ MFMA GEMM + fused al epilogue (row-major h, NODE-major als) ============
template <int OUT, int H, int CT, bool F32IN>
__global__ void gemm_k(const void* __restrict__ Xin, const unsigned short* __restrict__ Wp,
                       const float* __restrict__ a_src, const float* __restrict__ a_dst,
                       unsigned short* __restrict__ Hout, float* __restrict__ als,
                       float* __restrict__ ald) {
    const int wave = threadIdx.x >> 6;
    const int lane = threadIdx.x & 63;
    const int quad = lane >> 4;
    const int rl = lane & 15;
    const int r0 = blockIdx.x * 64;
    floatx4 acc[4][CT];
#pragma unroll
    for (int rt = 0; rt < 4; ++rt)
#pragma unroll
        for (int ct = 0; ct < CT; ++ct) acc[rt][ct] = {0.f, 0.f, 0.f, 0.f};

#pragma unroll
    for (int ks = 0; ks < 4; ++ks) {
        short8 a[4];
        const int c0k = ks * 32 + quad * 8;
#pragma unroll
        for (int rt = 0; rt < 4; ++rt) {
            int row = r0 + rt * 16 + rl;
            row = row < NN ? row : NN - 1;
            if (F32IN) {
                const float4* xp =
                    (const float4*)((const float*)Xin + (long long)row * 128 + c0k);
                const float4 v0 = xp[0];
                const float4 v1 = xp[1];
                short8 tt;
                tt[0] = (short)f2b(v0.x);
                tt[1] = (short)f2b(v0.y);
                tt[2] = (short)f2b(v0.z);
                tt[3] = (short)f2b(v0.w);
                tt[4] = (short)f2b(v1.x);
                tt[5] = (short)f2b(v1.y);
                tt[6] = (short)f2b(v1.z);
                tt[7] = (short)f2b(v1.w);
                a[rt] = tt;
            } else {
                a[rt] = *(const short8*)((const unsigned short*)Xin +
                                         (long long)row * 128 + c0k);
            }
        }
#pragma unroll
        for (int ct = 0; ct < CT; ++ct) {
            const int ctg = wave * CT + ct;
            const short8 b = *(const short8*)(Wp + (((ctg * 4 + ks) * 64 + lane) << 3));
#pragma unroll
            for (int rt = 0; rt < 4; ++rt)
                acc[rt][ct] = __builtin_amdgcn_mfma_f32_16x16x32_bf16(a[rt], b, acc[rt][ct], 0, 0, 0);
        }
    }
#pragma unroll
    for (int rt = 0; rt < 4; ++rt) {
        const int rowbase = r0 + rt * 16 + quad * 4;
#pragma unroll
        for (int ct = 0; ct < CT; ++ct) {
            const int col = (wave * CT + ct) * 16 + rl;
#pragma unroll
            for (int r = 0; r < 4; ++r) {
                const int row = rowbase + r;
                if (row < NN) Hout[(long long)row * OUT + col] = f2b(acc[rt][ct][r]);
            }
        }
    }
    float asv[CT], adv[CT];
#pragma unroll
    for (int ct = 0; ct < CT; ++ct) {
        const int col = (wave * CT + ct) * 16 + rl;
        asv[ct] = a_src[col];
        adv[ct] = a_dst[col];
    }
#pragma unroll
    for (int rt = 0; rt < 4; ++rt) {
#pragma unroll
        for (int r = 0; r < 4; ++r) {
            const int row = r0 + rt * 16 + quad * 4 + r;
            float ps[CT / 2], pd[CT / 2];
#pragma unroll
            for (int hh = 0; hh < CT / 2; ++hh) {
                ps[hh] = acc[rt][2 * hh][r] * asv[2 * hh] + acc[rt][2 * hh + 1][r] * asv[2 * hh + 1];
                pd[hh] = acc[rt][2 * hh][r] * adv[2 * hh] + acc[rt][2 * hh + 1][r] * adv[2 * hh + 1];
#pragma unroll
                for (int m = 8; m >= 1; m >>= 1) {
                    ps[hh] += __shfl_xor(ps[hh], m, 64);
                    pd[hh] += __shfl_xor(pd[hh], m, 64);
                }
            }
            if (rl == 0 && row < NN) {
#pragma unroll
                for (int hh = 0; hh < CT / 2; ++hh) {
                    const int hd = wave * (CT / 2) + hh;
                    als[(long long)row * H + hd] = ps[hh];
                    ald[(long long)row * H + hd] = pd[hh];
                }
            }
        }
    }
}

// ============ conv1 gather: row-major, one wave/node, 8/4/1 unroll, EPW=2 ============
__global__ void gather1_k(const int* __restrict__ start, const int* __restrict__ csr,
                          const float* __restrict__ als, const float* __restrict__ ald,
                          const unsigned short* __restrict__ Hin,
                          const float* __restrict__ bias, unsigned short* __restrict__ outp) {
    const int d = blockIdx.x;
    const int lane = threadIdx.x;
    const int cl = lane & 31;
    const int slot = lane >> 5;
    const int hd = cl >> 3;
    const int beg = start[d], end = start[d + 1];
    const float aldd = ald[(long long)d * H1 + hd];
    float a0 = 0.f, a1 = 0.f, a2 = 0.f, a3 = 0.f, den = 0.f;
    int i = beg + slot;
    for (; i + 7 * 2 < end; i += 8 * 2) {
        int s[8];
        float l[8];
        ushort4 hv[8];
#pragma unroll
        for (int k = 0; k < 8; ++k) s[k] = csr[i + k * 2];
#pragma unroll
        for (int k = 0; k < 8; ++k) l[k] = als[(long long)s[k] * H1 + hd] + aldd;
#pragma unroll
        for (int k = 0; k < 8; ++k) hv[k] = *(const ushort4*)(Hin + (long long)s[k] * 128 + cl * 4);
#pragma unroll
        for (int k = 0; k < 8; ++k) {
            float lg = l[k] > 0.f ? l[k] : NEG_SLOPE * l[k];
            const float w = __expf(lg);
            den += w;
            a0 += w * b2f(hv[k].x);
            a1 += w * b2f(hv[k].y);
            a2 += w * b2f(hv[k].z);
            a3 += w * b2f(hv[k].w);
        }
    }
    for (; i + 3 * 2 < end; i += 4 * 2) {
        int s[4];
        float l[4];
        ushort4 hv[4];
#pragma unroll
        for (int k = 0; k < 4; ++k) s[k] = csr[i + k * 2];
#pragma unroll
        for (int k = 0; k < 4; ++k) l[k] = als[(long long)s[k] * H1 + hd] + aldd;
#pragma unroll
        for (int k = 0; k < 4; ++k) hv[k] = *(const ushort4*)(Hin + (long long)s[k] * 128 + cl * 4);
#pragma unroll
        for (int k = 0; k < 4; ++k) {
            float lg = l[k] > 0.f ? l[k] : NEG_SLOPE * l[k];
            const float w = __expf(lg);
            den += w;
            a0 += w * b2f(hv[k].x);
            a1 += w * b2f(hv[k].y);
            a2 += w * b2f(hv[k].z);
            a3 += w * b2f(hv[k].w);
        }
    }
    for (; i < end; i += 2) {
        const int s = csr[i];
        float lg = als[(long long)s * H1 + hd] + aldd;
        lg = lg > 0.f ? lg : NEG_SLOPE * lg;
        const float w = __expf(lg);
        const ushort4 hv = *(const ushort4*)(Hin + (long long)s * 128 + cl * 4);
        den += w;
        a0 += w * b2f(hv.x);
        a1 += w * b2f(hv.y);
        a2 += w * b2f(hv.z);
        a3 += w * b2f(hv.w);
    }
    a0 += __shfl_xor(a0, 32, 64);
    a1 += __shfl_xor(a1, 32, 64);
    a2 += __shfl_xor(a2, 32, 64);
    a3 += __shfl_xor(a3, 32, 64);
    den += __shfl_xor(den, 32, 64);
    if (lane < 32) {
        const float inv = 1.f / (den + 1e-16f);
        const int c0 = cl * 4;
        float v0 = a0 * inv + bias[c0];
        float v1 = a1 * inv + bias[c0 + 1];
        float v2 = a2 * inv + bias[c0 + 2];
        float v3 = a3 * inv + bias[c0 + 3];
        v0 = v0 > 0.f ? v0 : 0.f;
        v1 = v1 > 0.f ? v1 : 0.f;
        v2 = v2 > 0.f ? v2 : 0.f;
        v3 = v3 > 0.f ? v3 : 0.f;
        ushort4 o;
        o.x = f2b(v0);
        o.y = f2b(v1);
        o.z = f2b(v2);
        o.w = f2b(v3);
        *(ushort4*)(outp + (long long)d * 128 + c0) = o;
    }
}

// ============ conv2 gather: row-major, one wave/node, 8/4/1 unroll ============
__global__ void gather2_k(const int* __restrict__ start, const int* __restrict__ csr,
                          const float* __restrict__ als, const float* __restrict__ ald,
                          const unsigned short* __restrict__ Hin,
                          const float* __restrict__ bias, unsigned short* __restrict__ outp) {
    const int d = blockIdx.x;
    const int lane = threadIdx.x;
    const int hd = lane >> 3;
    const int beg = start[d], end = start[d + 1];
    const float aldd = ald[(long long)d * H2 + hd];
    float a0 = 0.f, a1 = 0.f, a2 = 0.f, a3 = 0.f, den = 0.f;
    int i = beg;
    for (; i + 7 < end; i += 8) {
        int s[8];
        float l[8];
        ushort4 hv[8];
#pragma unroll
        for (int k = 0; k < 8; ++k) s[k] = csr[i + k];
#pragma unroll
        for (int k = 0; k < 8; ++k) l[k] = als[(long long)s[k] * H2 + hd] + aldd;
#pragma unroll
        for (int k = 0; k < 8; ++k) hv[k] = *(const ushort4*)(Hin + (long long)s[k] * 256 + lane * 4);
#pragma unroll
        for (int k = 0; k < 8; ++k) {
            float lg = l[k] > 0.f ? l[k] : NEG_SLOPE * l[k];
            const float w = __expf(lg);
            den += w;
            a0 += w * b2f(hv[k].x);
            a1 += w * b2f(hv[k].y);
            a2 += w * b2f(hv[k].z);
            a3 += w * b2f(hv[k].w);
        }
    }
    for (; i + 3 < end; i += 4) {
        int s[4];
        float l[4];
        ushort4 hv[4];
#pragma unroll
        for (int k = 0; k < 4; ++k) s[k] = csr[i + k];
#pragma unroll
        for (int k = 0; k < 4; ++k) l[k] = als[(long long)s[k] * H2 + hd] + aldd;
#pragma unroll
        for (int k = 0; k < 4; ++k) hv[k] = *(const ushort4*)(Hin + (long long)s[k] * 256 + lane * 4);
#pragma unroll
        for (int k = 0; k < 4; ++k) {
            float lg = l[k] > 0.f ? l[k] : NEG_SLOPE * l[k];
            const float w = __expf(lg);
            den += w;
            a0 += w * b2f(hv[k].x);
            a1 += w * b2f(hv[k].y);
            a2 += w * b2f(hv[k].z);
            a3 += w * b2f(hv[k].w);
        }
    }
    for (; i < end; ++i) {
        const int s = csr[i];
        float lg = als[(long long)s * H2 + hd] + aldd;
        lg = lg > 0.f ? lg : NEG_SLOPE * lg;
        const float w = __expf(lg);
        const ushort4 hv = *(const ushort4*)(Hin + (long long)s * 256 + lane * 4);
        den += w;
        a0 += w * b2f(hv.x);
        a1 += w * b2f(hv.y);
        a2 += w * b2f(hv.z);
        a3 += w * b2f(hv.w);
    }
    const float inv = 1.f / (den + 1e-16f);
    const int c0 = lane * 4;
    ushort4 o;
    o.x = f2b(a0 * inv + bias[c0]);
    o.y = f2b(a1 * inv + bias[c0 + 1]);
    o.z = f2b(a2 * inv + bias[c0 + 2]);
    o.w = f2b(a3 * inv + bias[c0 + 3]);
    *(ushort4*)(outp + (long long)d * 256 + c0) = o;
}

// ============ decode: XCD-sliced partial dots ============
__global__ void decode_s_k(const int* __restrict__ pei, const int* __restrict__ nei,
                           const unsigned short* __restrict__ z2, float* __restrict__ part) {
    const int s = blockIdx.x & 7;
    const int g = blockIdx.x >> 3;
    const int wave = threadIdx.x >> 6, lane = threadIdx.x & 63;
    const int slot = lane >> 3, cl = lane & 7;
    const int idx = g * 32 + wave * 8 + slot;
    if (idx >= 2 * E_DEC) return;
    int a, b;
    if (idx < E_DEC) {
        a = pei[idx];
        b = pei[E_DEC + idx];
    } else {
        const int j = idx - E_DEC;
        a = nei[j];
        b = nei[E_DEC + j];
    }
    const ushort4 ua = *(const ushort4*)(z2 + (long long)a * 256 + s * 32 + cl * 4);
    const ushort4 ub = *(const ushort4*)(z2 + (long long)b * 256 + s * 32 + cl * 4);
    float sum = b2f(ua.x) * b2f(ub.x) + b2f(ua.y) * b2f(ub.y) +
                b2f(ua.z) * b2f(ub.z) + b2f(ua.w) * b2f(ub.w);
    sum += __shfl_xor(sum, 4, 64);
    sum += __shfl_xor(sum, 2, 64);
    sum += __shfl_xor(sum, 1, 64);
    if (cl == 0) part[(long long)s * (2 * E_DEC) + idx] = sum;
}

__global__ void reduce_k(const float* __restrict__ part, float* __restrict__ out) {
    const int i = blockIdx.x * 256 + threadIdx.x;
    if (i >= 2 * E_DEC) return;
    float s = 0.f;
#pragma unroll
    for (int k = 0; k < 8; ++k) s += part[(long long)k * (2 * E_DEC) + i];
    out[i] = s;
}

extern "C" void kernel_launch(void* const* d_in, const int* in_sizes, int n_in,
                              void* d_out, int out_size, void* d_ws, size_t ws_size,
                              hipStream_t stream) {
    const float* x = (const float*)d_in[0];
    const int* ei = (const int*)d_in[1];
    const int* pei = (const int*)d_in[2];
    const int* nei = (const int*)d_in[3];
    const float* W1 = (const float*)d_in[4];
    const float* as1 = (const float*)d_in[5];
    const float* ad1 = (const float*)d_in[6];
    const float* b1 = (const float*)d_in[7];
    const float* W2 = (const float*)d_in[8];
    const float* as2 = (const float*)d_in[9];
    const float* ad2 = (const float*)d_in[10];
    const float* b2 = (const float*)d_in[11];
    float* out = (float*)d_out;

    // ---- workspace layout ----
    unsigned short* h1 = (unsigned short*)d_ws;              // NN*128 row-major
    unsigned short* h2 = h1 + (long long)NN * 128;           // NN*256 row-major
    unsigned short* z2 = h2 + (long long)NN * 256;           // NN*256 row-major
    unsigned short* z1 = z2 + (long long)NN * 256;           // NN*128 row-major
    unsigned short* wp1 = z1 + (long long)NN * 128;          // 128*128
    unsigned short* wp2 = wp1 + 128 * 128;                   // 128*256
    float* als1 = (float*)(wp2 + 128 * 256);                 // NN*H1 node-major
    float* ald1 = als1 + NN * H1;
    float* als2 = ald1 + NN * H1;                            // NN*H2 node-major
    float* ald2 = als2 + NN * H2;
    float* part = ald2 + NN * H2;                            // 8 * 2*E_DEC
    int* counts_p = (int*)(part + 8 * 2 * E_DEC);            // 8*NN
    int* start = counts_p + 8 * NN;                          // NN+1
    int* offs = start + NN + 1;                              // 8*NN
    int* rank = offs + 8 * NN;                               // EE
    int* agg = rank + EE;                                    // 256
    int* done = agg + 256;                                   // 1 (zeroed by hist_pack)
    int* csr = done + 1;                                     // ET
    int* probe = csr + ET;                                   // 1 (never written)

    // ---- CSR build (XCD-local partial hists + rank; fused scan) + W pack ----
    hist_pack_k<<<HIST_BLOCKS + PACK_BLOCKS + 1, 256, 0, stream>>>(
        ei, counts_p, probe, rank, W1, wp1, W2, wp2, done);
    scanfused_k<<<NB_SCAN, 256, 0, stream>>>(counts_p, probe, agg, done, start, offs, csr);
    scatter_k<<<HIST_BLOCKS, 256, 0, stream>>>(ei, rank, offs, csr);

    // ---- conv1 ----
    gemm_k<128, H1, 2, true><<<(NN + 63) / 64, 256, 0, stream>>>(
        x, wp1, as1, ad1, h1, als1, ald1);
    gather1_k<<<NN, 64, 0, stream>>>(start, csr, als1, ald1, h1, b1, z1);

    // ---- conv2 ----
    gemm_k<256, H2, 4, false><<<(NN + 63) / 64, 256, 0, stream>>>(
        z1, wp2, as2, ad2, h2, als2, ald2);
    gather2_k<<<NN, 64, 0, stream>>>(start, csr, als2, ald2, h2, b2, z2);

    // ---- decode: XCD-sliced partials + reduce ----
    decode_s_k<<<8 * ((2 * E_DEC + 31) / 32), 256, 0, stream>>>(pei, nei, z2, part);
    reduce_k<<<(2 * E_DEC + 255) / 256, 256, 0, stream>>>(part, out);
}

// Round 20
// 335.337 us; speedup vs baseline: 1.0760x; 1.0131x over previous
//
#include <hip/hip_runtime.h>
#include <hip/hip_bf16.h>

#define NN 50000
#define EE 800000
#define ET (EE + NN)
#define F_IN 128
#define HID 32
#define H1 4
#define H2 8
#define E_DEC 100000
#define NEG_SLOPE 0.2f

typedef __attribute__((ext_vector_type(8))) short short8;
typedef __attribute__((ext_vector_type(4))) float floatx4;

__device__ __forceinline__ unsigned short f2b(float f) {
    __hip_bfloat16 h = __float2bfloat16(f);
    return *reinterpret_cast<unsigned short*>(&h);
}
__device__ __forceinline__ float b2f(unsigned short u) {
    return __uint_as_float(((unsigned int)u) << 16);
}

// ============ merged: XCD-local histogram+rank + pack W1 + pack W2 ============
__device__ __forceinline__ void packW_one(const float* __restrict__ W,
                                          unsigned short* __restrict__ Wp, int OUT, int id) {
    const int ctg = id >> 8;
    const int ln = id & 63;
    const int col = ctg * 16 + (ln & 15);
    const int k0 = ((id >> 6) & 3) * 32 + ((ln >> 4) & 3) * 8;
    ushort4 lo, hi;
    lo.x = f2b(W[(k0 + 0) * OUT + col]);
    lo.y = f2b(W[(k0 + 1) * OUT + col]);
    lo.z = f2b(W[(k0 + 2) * OUT + col]);
    lo.w = f2b(W[(k0 + 3) * OUT + col]);
    hi.x = f2b(W[(k0 + 4) * OUT + col]);
    hi.y = f2b(W[(k0 + 5) * OUT + col]);
    hi.z = f2b(W[(k0 + 6) * OUT + col]);
    hi.w = f2b(W[(k0 + 7) * OUT + col]);
    ((ushort4*)Wp)[id * 2] = lo;
    ((ushort4*)Wp)[id * 2 + 1] = hi;
}

#define HIST_BLOCKS ((EE / 4 + 255) / 256)   // 782
#define PACK_BLOCKS ((6144 + 255) / 256)     // 24

__global__ void hist_pack_k(const int* __restrict__ ei, int* __restrict__ counts_p,
                            const int* __restrict__ probe, int* __restrict__ rank,
                            const float* __restrict__ W1, unsigned short* __restrict__ wp1,
                            const float* __restrict__ W2, unsigned short* __restrict__ wp2) {
    if (blockIdx.x < HIST_BLOCKS) {
        const int t = blockIdx.x * 256 + threadIdx.x;
        if (t >= EE / 4) return;
        const int pv = probe[0];
        int* cp = counts_p + (blockIdx.x & 7) * NN;
        const int4 d4 = ((const int4*)(ei + EE))[t];
        int4 r4;
        r4.x = atomicAdd(&cp[d4.x], 1) - pv;
        r4.y = atomicAdd(&cp[d4.y], 1) - pv;
        r4.z = atomicAdd(&cp[d4.z], 1) - pv;
        r4.w = atomicAdd(&cp[d4.w], 1) - pv;
        ((int4*)rank)[t] = r4;
    } else {
        const int id = (blockIdx.x - HIST_BLOCKS) * 256 + threadIdx.x;
        if (id < 2048) packW_one(W1, wp1, 128, id);
        else if (id < 6144) packW_one(W2, wp2, 256, id - 2048);
    }
}

// ============ hierarchical exclusive scan over node degrees ============
__global__ void scan1_k(const int* __restrict__ counts_p, const int* __restrict__ probe,
                        int* __restrict__ bsum) {
    __shared__ int sh[256];
    const unsigned pv = (unsigned)probe[0];
    int t = threadIdx.x;
    int i = blockIdx.x * 256 + t;
    int deg = 0;
    if (i < NN) {
        unsigned sum = 0;
#pragma unroll
        for (int s = 0; s < 8; ++s) sum += (unsigned)counts_p[s * NN + i];
        deg = (int)(sum - 8u * pv) + 1;
    }
    sh[t] = deg;
    __syncthreads();
    for (int off = 128; off > 0; off >>= 1) {
        if (t < off) sh[t] += sh[t + off];
        __syncthreads();
    }
    if (t == 0) bsum[blockIdx.x] = sh[0];
}

__global__ void scan2_k(int* __restrict__ bsum, int nb, int* __restrict__ start) {
    __shared__ int sh[256];
    int t = threadIdx.x;
    int v = (t < nb) ? bsum[t] : 0;
    sh[t] = v;
    __syncthreads();
    for (int off = 1; off < 256; off <<= 1) {
        int u = (t >= off) ? sh[t - off] : 0;
        __syncthreads();
        sh[t] += u;
        __syncthreads();
    }
    if (t < nb) bsum[t] = sh[t] - v;
    if (t == 0) start[NN] = ET;
}

// scan3: start[], per-slice offsets offs[s][i], self-loop in LAST slot.
__global__ void scan3_k(const int* __restrict__ counts_p, const int* __restrict__ probe,
                        const int* __restrict__ bsum, int* __restrict__ start,
                        int* __restrict__ offs, int* __restrict__ csr) {
    __shared__ int sh[256];
    const unsigned pv = (unsigned)probe[0];
    int t = threadIdx.x;
    int i = blockIdx.x * 256 + t;
    int part[8];
    int deg = 0;
    if (i < NN) {
        deg = 1;
#pragma unroll
        for (int s = 0; s < 8; ++s) {
            part[s] = (int)((unsigned)counts_p[s * NN + i] - pv);
            deg += part[s];
        }
    }
    sh[t] = deg;
    __syncthreads();
    for (int off = 1; off < 256; off <<= 1) {
        int u = (t >= off) ? sh[t - off] : 0;
        __syncthreads();
        sh[t] += u;
        __syncthreads();
    }
    int excl = sh[t] - deg + bsum[blockIdx.x];
    if (i < NN) {
        start[i] = excl;
        int o = excl;
#pragma unroll
        for (int s = 0; s < 8; ++s) {
            offs[s * NN + i] = o;
            o += part[s];
        }
        csr[o] = i;   // self-loop last
    }
}

// ============ scatter: rank+offs based, NO atomics ============
__global__ void scatter_k(const int* __restrict__ ei, const int* __restrict__ rank,
                          const int* __restrict__ offs, int* __restrict__ csr) {
    const int t = blockIdx.x * 256 + threadIdx.x;
    if (t >= EE / 4) return;
    const int* off = offs + (blockIdx.x & 7) * NN;
    const int4 s4 = ((const int4*)ei)[t];
    const int4 d4 = ((const int4*)(ei + EE))[t];
    const int4 r4 = ((const int4*)rank)[t];
    csr[off[d4.x] + r4.x] = s4.x;
    csr[off[d4.y] + r4.y] = s4.y;
    csr[off[d4.z] + r4.z] = s4.z;
    csr[off[d4.w] + r4.w] = s4.w;
}

// ============ MFMA GEMM + fused al epilogue (row-major h, NODE-major als) ============
template <int OUT, int H, int CT, bool F32IN>
__global__ void gemm_k(const void* __restrict__ Xin, const unsigned short* __restrict__ Wp,
                       const float* __restrict__ a_src, const float* __restrict__ a_dst,
                       unsigned short* __restrict__ Hout, float* __restrict__ als,
                       float* __restrict__ ald) {
    const int wave = threadIdx.x >> 6;
    const int lane = threadIdx.x & 63;
    const int quad = lane >> 4;
    const int rl = lane & 15;
    const int r0 = blockIdx.x * 64;
    floatx4 acc[4][CT];
#pragma unroll
    for (int rt = 0; rt < 4; ++rt)
#pragma unroll
        for (int ct = 0; ct < CT; ++ct) acc[rt][ct] = {0.f, 0.f, 0.f, 0.f};

#pragma unroll
    for (int ks = 0; ks < 4; ++ks) {
        short8 a[4];
        const int c0k = ks * 32 + quad * 8;
#pragma unroll
        for (int rt = 0; rt < 4; ++rt) {
            int row = r0 + rt * 16 + rl;
            row = row < NN ? row : NN - 1;
            if (F32IN) {
                const float4* xp =
                    (const float4*)((const float*)Xin + (long long)row * 128 + c0k);
                const float4 v0 = xp[0];
                const float4 v1 = xp[1];
                short8 tt;
                tt[0] = (short)f2b(v0.x);
                tt[1] = (short)f2b(v0.y);
                tt[2] = (short)f2b(v0.z);
                tt[3] = (short)f2b(v0.w);
                tt[4] = (short)f2b(v1.x);
                tt[5] = (short)f2b(v1.y);
                tt[6] = (short)f2b(v1.z);
                tt[7] = (short)f2b(v1.w);
                a[rt] = tt;
            } else {
                a[rt] = *(const short8*)((const unsigned short*)Xin +
                                         (long long)row * 128 + c0k);
            }
        }
#pragma unroll
        for (int ct = 0; ct < CT; ++ct) {
            const int ctg = wave * CT + ct;
            const short8 b = *(const short8*)(Wp + (((ctg * 4 + ks) * 64 + lane) << 3));
#pragma unroll
            for (int rt = 0; rt < 4; ++rt)
                acc[rt][ct] = __builtin_amdgcn_mfma_f32_16x16x32_bf16(a[rt], b, acc[rt][ct], 0, 0, 0);
        }
    }
#pragma unroll
    for (int rt = 0; rt < 4; ++rt) {
        const int rowbase = r0 + rt * 16 + quad * 4;
#pragma unroll
        for (int ct = 0; ct < CT; ++ct) {
            const int col = (wave * CT + ct) * 16 + rl;
#pragma unroll
            for (int r = 0; r < 4; ++r) {
                const int row = rowbase + r;
                if (row < NN) Hout[(long long)row * OUT + col] = f2b(acc[rt][ct][r]);
            }
        }
    }
    float asv[CT], adv[CT];
#pragma unroll
    for (int ct = 0; ct < CT; ++ct) {
        const int col = (wave * CT + ct) * 16 + rl;
        asv[ct] = a_src[col];
        adv[ct] = a_dst[col];
    }
#pragma unroll
    for (int rt = 0; rt < 4; ++rt) {
#pragma unroll
        for (int r = 0; r < 4; ++r) {
            const int row = r0 + rt * 16 + quad * 4 + r;
            float ps[CT / 2], pd[CT / 2];
#pragma unroll
            for (int hh = 0; hh < CT / 2; ++hh) {
                ps[hh] = acc[rt][2 * hh][r] * asv[2 * hh] + acc[rt][2 * hh + 1][r] * asv[2 * hh + 1];
                pd[hh] = acc[rt][2 * hh][r] * adv[2 * hh] + acc[rt][2 * hh + 1][r] * adv[2 * hh + 1];
#pragma unroll
                for (int m = 8; m >= 1; m >>= 1) {
                    ps[hh] += __shfl_xor(ps[hh], m, 64);
                    pd[hh] += __shfl_xor(pd[hh], m, 64);
                }
            }
            if (rl == 0 && row < NN) {
#pragma unroll
                for (int hh = 0; hh < CT / 2; ++hh) {
                    const int hd = wave * (CT / 2) + hh;
                    als[(long long)row * H + hd] = ps[hh];
                    ald[(long long)row * H + hd] = pd[hh];
                }
            }
        }
    }
}

// ============ conv1 gather: row-major, wave-per-node, 4 nodes/block ============
__global__ void gather1_k(const int* __restrict__ start, const int* __restrict__ csr,
                          const float* __restrict__ als, const float* __restrict__ ald,
                          const unsigned short* __restrict__ Hin,
                          const float* __restrict__ bias, unsigned short* __restrict__ outp) {
    const int d = blockIdx.x * 4 + (threadIdx.x >> 6);
    if (d >= NN) return;
    const int lane = threadIdx.x & 63;
    const int cl = lane & 31;
    const int slot = lane >> 5;
    const int hd = cl >> 3;
    const int beg = start[d], end = start[d + 1];
    const float aldd = ald[(long long)d * H1 + hd];
    float a0 = 0.f, a1 = 0.f, a2 = 0.f, a3 = 0.f, den = 0.f;
    int i = beg + slot;
    for (; i + 7 * 2 < end; i += 8 * 2) {
        int s[8];
        float l[8];
        ushort4 hv[8];
#pragma unroll
        for (int k = 0; k < 8; ++k) s[k] = csr[i + k * 2];
#pragma unroll
        for (int k = 0; k < 8; ++k) l[k] = als[(long long)s[k] * H1 + hd] + aldd;
#pragma unroll
        for (int k = 0; k < 8; ++k) hv[k] = *(const ushort4*)(Hin + (long long)s[k] * 128 + cl * 4);
#pragma unroll
        for (int k = 0; k < 8; ++k) {
            float lg = l[k] > 0.f ? l[k] : NEG_SLOPE * l[k];
            const float w = __expf(lg);
            den += w;
            a0 += w * b2f(hv[k].x);
            a1 += w * b2f(hv[k].y);
            a2 += w * b2f(hv[k].z);
            a3 += w * b2f(hv[k].w);
        }
    }
    for (; i + 3 * 2 < end; i += 4 * 2) {
        int s[4];
        float l[4];
        ushort4 hv[4];
#pragma unroll
        for (int k = 0; k < 4; ++k) s[k] = csr[i + k * 2];
#pragma unroll
        for (int k = 0; k < 4; ++k) l[k] = als[(long long)s[k] * H1 + hd] + aldd;
#pragma unroll
        for (int k = 0; k < 4; ++k) hv[k] = *(const ushort4*)(Hin + (long long)s[k] * 128 + cl * 4);
#pragma unroll
        for (int k = 0; k < 4; ++k) {
            float lg = l[k] > 0.f ? l[k] : NEG_SLOPE * l[k];
            const float w = __expf(lg);
            den += w;
            a0 += w * b2f(hv[k].x);
            a1 += w * b2f(hv[k].y);
            a2 += w * b2f(hv[k].z);
            a3 += w * b2f(hv[k].w);
        }
    }
    for (; i < end; i += 2) {
        const int s = csr[i];
        float lg = als[(long long)s * H1 + hd] + aldd;
        lg = lg > 0.f ? lg : NEG_SLOPE * lg;
        const float w = __expf(lg);
        const ushort4 hv = *(const ushort4*)(Hin + (long long)s * 128 + cl * 4);
        den += w;
        a0 += w * b2f(hv.x);
        a1 += w * b2f(hv.y);
        a2 += w * b2f(hv.z);
        a3 += w * b2f(hv.w);
    }
    a0 += __shfl_xor(a0, 32, 64);
    a1 += __shfl_xor(a1, 32, 64);
    a2 += __shfl_xor(a2, 32, 64);
    a3 += __shfl_xor(a3, 32, 64);
    den += __shfl_xor(den, 32, 64);
    if (lane < 32) {
        const float inv = 1.f / (den + 1e-16f);
        const int c0 = cl * 4;
        float v0 = a0 * inv + bias[c0];
        float v1 = a1 * inv + bias[c0 + 1];
        float v2 = a2 * inv + bias[c0 + 2];
        float v3 = a3 * inv + bias[c0 + 3];
        v0 = v0 > 0.f ? v0 : 0.f;
        v1 = v1 > 0.f ? v1 : 0.f;
        v2 = v2 > 0.f ? v2 : 0.f;
        v3 = v3 > 0.f ? v3 : 0.f;
        ushort4 o;
        o.x = f2b(v0);
        o.y = f2b(v1);
        o.z = f2b(v2);
        o.w = f2b(v3);
        *(ushort4*)(outp + (long long)d * 128 + c0) = o;
    }
}

// ============ conv2 gather: row-major, wave-per-node, 4 nodes/block ============
__global__ void gather2_k(const int* __restrict__ start, const int* __restrict__ csr,
                          const float* __restrict__ als, const float* __restrict__ ald,
                          const unsigned short* __restrict__ Hin,
                          const float* __restrict__ bias, unsigned short* __restrict__ outp) {
    const int d = blockIdx.x * 4 + (threadIdx.x >> 6);
    if (d >= NN) return;
    const int lane = threadIdx.x & 63;
    const int hd = lane >> 3;
    const int beg = start[d], end = start[d + 1];
    const float aldd = ald[(long long)d * H2 + hd];
    float a0 = 0.f, a1 = 0.f, a2 = 0.f, a3 = 0.f, den = 0.f;
    int i = beg;
    for (; i + 7 < end; i += 8) {
        int s[8];
        float l[8];
        ushort4 hv[8];
#pragma unroll
        for (int k = 0; k < 8; ++k) s[k] = csr[i + k];
#pragma unroll
        for (int k = 0; k < 8; ++k) l[k] = als[(long long)s[k] * H2 + hd] + aldd;
#pragma unroll
        for (int k = 0; k < 8; ++k) hv[k] = *(const ushort4*)(Hin + (long long)s[k] * 256 + lane * 4);
#pragma unroll
        for (int k = 0; k < 8; ++k) {
            float lg = l[k] > 0.f ? l[k] : NEG_SLOPE * l[k];
            const float w = __expf(lg);
            den += w;
            a0 += w * b2f(hv[k].x);
            a1 += w * b2f(hv[k].y);
            a2 += w * b2f(hv[k].z);
            a3 += w * b2f(hv[k].w);
        }
    }
    for (; i + 3 < end; i += 4) {
        int s[4];
        float l[4];
        ushort4 hv[4];
#pragma unroll
        for (int k = 0; k < 4; ++k) s[k] = csr[i + k];
#pragma unroll
        for (int k = 0; k < 4; ++k) l[k] = als[(long long)s[k] * H2 + hd] + aldd;
#pragma unroll
        for (int k = 0; k < 4; ++k) hv[k] = *(const ushort4*)(Hin + (long long)s[k] * 256 + lane * 4);
#pragma unroll
        for (int k = 0; k < 4; ++k) {
            float lg = l[k] > 0.f ? l[k] : NEG_SLOPE * l[k];
            const float w = __expf(lg);
            den += w;
            a0 += w * b2f(hv[k].x);
            a1 += w * b2f(hv[k].y);
            a2 += w * b2f(hv[k].z);
            a3 += w * b2f(hv[k].w);
        }
    }
    for (; i < end; ++i) {
        const int s = csr[i];
        float lg = als[(long long)s * H2 + hd] + aldd;
        lg = lg > 0.f ? lg : NEG_SLOPE * lg;
        const float w = __expf(lg);
        const ushort4 hv = *(const ushort4*)(Hin + (long long)s * 256 + lane * 4);
        den += w;
        a0 += w * b2f(hv.x);
        a1 += w * b2f(hv.y);
        a2 += w * b2f(hv.z);
        a3 += w * b2f(hv.w);
    }
    const float inv = 1.f / (den + 1e-16f);
    const int c0 = lane * 4;
    ushort4 o;
    o.x = f2b(a0 * inv + bias[c0]);
    o.y = f2b(a1 * inv + bias[c0 + 1]);
    o.z = f2b(a2 * inv + bias[c0 + 2]);
    o.w = f2b(a3 * inv + bias[c0 + 3]);
    *(ushort4*)(outp + (long long)d * 256 + c0) = o;
}

// ============ decode: XCD-sliced partial dots ============
__global__ void decode_s_k(const int* __restrict__ pei, const int* __restrict__ nei,
                           const unsigned short* __restrict__ z2, float* __restrict__ part) {
    const int s = blockIdx.x & 7;
    const int g = blockIdx.x >> 3;
    const int wave = threadIdx.x >> 6, lane = threadIdx.x & 63;
    const int slot = lane >> 3, cl = lane & 7;
    const int idx = g * 32 + wave * 8 + slot;
    if (idx >= 2 * E_DEC) return;
    int a, b;
    if (idx < E_DEC) {
        a = pei[idx];
        b = pei[E_DEC + idx];
    } else {
        const int j = idx - E_DEC;
        a = nei[j];
        b = nei[E_DEC + j];
    }
    const ushort4 ua = *(const ushort4*)(z2 + (long long)a * 256 + s * 32 + cl * 4);
    const ushort4 ub = *(const ushort4*)(z2 + (long long)b * 256 + s * 32 + cl * 4);
    float sum = b2f(ua.x) * b2f(ub.x) + b2f(ua.y) * b2f(ub.y) +
                b2f(ua.z) * b2f(ub.z) + b2f(ua.w) * b2f(ub.w);
    sum += __shfl_xor(sum, 4, 64);
    sum += __shfl_xor(sum, 2, 64);
    sum += __shfl_xor(sum, 1, 64);
    if (cl == 0) part[(long long)s * (2 * E_DEC) + idx] = sum;
}

__global__ void reduce_k(const float* __restrict__ part, float* __restrict__ out) {
    const int i = blockIdx.x * 256 + threadIdx.x;
    if (i >= 2 * E_DEC) return;
    float s = 0.f;
#pragma unroll
    for (int k = 0; k < 8; ++k) s += part[(long long)k * (2 * E_DEC) + i];
    out[i] = s;
}

extern "C" void kernel_launch(void* const* d_in, const int* in_sizes, int n_in,
                              void* d_out, int out_size, void* d_ws, size_t ws_size,
                              hipStream_t stream) {
    const float* x = (const float*)d_in[0];
    const int* ei = (const int*)d_in[1];
    const int* pei = (const int*)d_in[2];
    const int* nei = (const int*)d_in[3];
    const float* W1 = (const float*)d_in[4];
    const float* as1 = (const float*)d_in[5];
    const float* ad1 = (const float*)d_in[6];
    const float* b1 = (const float*)d_in[7];
    const float* W2 = (const float*)d_in[8];
    const float* as2 = (const float*)d_in[9];
    const float* ad2 = (const float*)d_in[10];
    const float* b2 = (const float*)d_in[11];
    float* out = (float*)d_out;

    // ---- workspace layout ----
    unsigned short* h1 = (unsigned short*)d_ws;              // NN*128 row-major
    unsigned short* h2 = h1 + (long long)NN * 128;           // NN*256 row-major
    unsigned short* z2 = h2 + (long long)NN * 256;           // NN*256 row-major
    unsigned short* z1 = z2 + (long long)NN * 256;           // NN*128 row-major
    unsigned short* wp1 = z1 + (long long)NN * 128;          // 128*128
    unsigned short* wp2 = wp1 + 128 * 128;                   // 128*256
    float* als1 = (float*)(wp2 + 128 * 256);                 // NN*H1 node-major
    float* ald1 = als1 + NN * H1;
    float* als2 = ald1 + NN * H1;                            // NN*H2 node-major
    float* ald2 = als2 + NN * H2;
    float* part = ald2 + NN * H2;                            // 8 * 2*E_DEC
    int* counts_p = (int*)(part + 8 * 2 * E_DEC);            // 8*NN
    int* start = counts_p + 8 * NN;                          // NN+1
    int* offs = start + NN + 1;                              // 8*NN
    int* rank = offs + 8 * NN;                               // EE
    int* bsum = rank + EE;                                   // 256
    int* csr = bsum + 256;                                   // ET
    int* probe = csr + ET;                                   // 1 (never written)

    const int NB = (NN + 255) / 256;  // 196

    // ---- CSR build (XCD-local partial hists + rank) + W pack ----
    hist_pack_k<<<HIST_BLOCKS + PACK_BLOCKS, 256, 0, stream>>>(
        ei, counts_p, probe, rank, W1, wp1, W2, wp2);
    scan1_k<<<NB, 256, 0, stream>>>(counts_p, probe, bsum);
    scan2_k<<<1, 256, 0, stream>>>(bsum, NB, start);
    scan3_k<<<NB, 256, 0, stream>>>(counts_p, probe, bsum, start, offs, csr);
    scatter_k<<<HIST_BLOCKS, 256, 0, stream>>>(ei, rank, offs, csr);

    // ---- conv1 ----
    gemm_k<128, H1, 2, true><<<(NN + 63) / 64, 256, 0, stream>>>(
        x, wp1, as1, ad1, h1, als1, ald1);
    gather1_k<<<(NN + 3) / 4, 256, 0, stream>>>(start, csr, als1, ald1, h1, b1, z1);

    // ---- conv2 ----
    gemm_k<256, H2, 4, false><<<(NN + 63) / 64, 256, 0, stream>>>(
        z1, wp2, as2, ad2, h2, als2, ald2);
    gather2_k<<<(NN + 3) / 4, 256, 0, stream>>>(start, csr, als2, ald2, h2, b2, z2);

    // ---- decode: XCD-sliced partials + reduce ----
    decode_s_k<<<8 * ((2 * E_DEC + 31) / 32), 256, 0, stream>>>(pei, nei, z2, part);
    reduce_k<<<(2 * E_DEC + 255) / 256, 256, 0, stream>>>(part, out);
}